// Round 8
// baseline (154.766 us; speedup 1.0000x reference)
//
#include <hip/hip_runtime.h>
#include <hip/hip_bf16.h>
#include <math.h>

typedef short short8 __attribute__((ext_vector_type(8)));
typedef float f32x4 __attribute__((ext_vector_type(4)));

#define NROW   4096
#define DIM    128
#define NCLS   64
#define MAXM   128
#define NSTRIP 8
#define CPS    512     // columns per strip
#define NJT    8       // 64-column tiles per strip

__device__ __forceinline__ unsigned short f2bf(float f) {
    unsigned u = __builtin_bit_cast(unsigned, f);
    unsigned r = (u + 0x7fffu + ((u >> 16) & 1u)) >> 16;   // RNE
    return (unsigned short)r;
}

__device__ __forceinline__ short8 pack8(const float4& a, const float4& b) {
    short8 h;
    h[0] = (short)f2bf(a.x); h[1] = (short)f2bf(a.y);
    h[2] = (short)f2bf(a.z); h[3] = (short)f2bf(a.w);
    h[4] = (short)f2bf(b.x); h[5] = (short)f2bf(b.y);
    h[6] = (short)f2bf(b.z); h[7] = (short)f2bf(b.w);
    return h;
}

__device__ __forceinline__ float agentLoad(float* p) {
    return __hip_atomic_load(p, __ATOMIC_RELAXED, __HIP_MEMORY_SCOPE_AGENT);
}

// one block = (class c, strip s). Computes rn partials for its strip over the
// class's rows; last strip block of each class finishes the positive-pair loss;
// last class block writes the output. No global state needs zero-init:
// rnP/res are write-only slots, tickets use the mod trick (any start value works).
__global__ __launch_bounds__(256, 2) void fused_kernel(
        const float* __restrict__ X, const int* __restrict__ tgt,
        float* rnP, float* res, unsigned* tickC, unsigned* tickG,
        float* __restrict__ out)
{
    __shared__ __align__(16) unsigned short tCLS[MAXM * DIM];   // 32 KB
    __shared__ __align__(16) unsigned short tCOL[64 * DIM];     // 16 KB
    __shared__ float sqg[MAXM], rng[MAXM], sqc[64], s_red[16];
    __shared__ int   tjc[64], s_idx[MAXM], s_wsum[4];
    __shared__ int   s_win;

    const int t = threadIdx.x;
    const int w = t >> 6, l = t & 63, lr = l & 15, lg = l >> 4;
    const int c = blockIdx.x >> 3;          // class
    const int s = blockIdx.x & (NSTRIP - 1); // strip

    // ---- build ordered class row list by scanning tgt ----
    int mtot;
    {
        const int rbase = t * 16;
        int tv[16];
        {
            int4 a = *reinterpret_cast<const int4*>(tgt + rbase);
            int4 b = *reinterpret_cast<const int4*>(tgt + rbase + 4);
            int4 d = *reinterpret_cast<const int4*>(tgt + rbase + 8);
            int4 e = *reinterpret_cast<const int4*>(tgt + rbase + 12);
            tv[0]=a.x; tv[1]=a.y; tv[2]=a.z; tv[3]=a.w;
            tv[4]=b.x; tv[5]=b.y; tv[6]=b.z; tv[7]=b.w;
            tv[8]=d.x; tv[9]=d.y; tv[10]=d.z; tv[11]=d.w;
            tv[12]=e.x; tv[13]=e.y; tv[14]=e.z; tv[15]=e.w;
        }
        int cnt = 0;
        #pragma unroll
        for (int k = 0; k < 16; ++k) cnt += (tv[k] == c) ? 1 : 0;
        int sc = cnt;                                    // wave inclusive scan
        #pragma unroll
        for (int d2 = 1; d2 < 64; d2 <<= 1) {
            int u = __shfl_up(sc, d2);
            if (l >= d2) sc += u;
        }
        if (l == 63) s_wsum[w] = sc;
        __syncthreads();
        int woff = 0;
        if (w > 0) woff += s_wsum[0];
        if (w > 1) woff += s_wsum[1];
        if (w > 2) woff += s_wsum[2];
        int off = woff + sc - cnt;                       // exclusive prefix
        #pragma unroll
        for (int k = 0; k < 16; ++k) {
            if (tv[k] == c) { if (off < MAXM) s_idx[off] = rbase + k; ++off; }
        }
        mtot = s_wsum[0] + s_wsum[1] + s_wsum[2] + s_wsum[3];
    }
    const int mm = mtot < MAXM ? mtot : MAXM;
    __syncthreads();                                     // s_idx ready

    // ---- stage class rows: 4 threads/row, 32 cols each, bf16 + swizzle ----
    {
        const int sub = t & 3;
        #pragma unroll
        for (int r0 = 0; r0 < MAXM; r0 += 64) {
            int row = r0 + (t >> 2);
            if (row < mm) {
                int ri = s_idx[row];
                const float4* src = reinterpret_cast<const float4*>(X + (size_t)ri * DIM + sub * 32);
                float4 buf[8];
                #pragma unroll
                for (int q = 0; q < 8; ++q) buf[q] = src[q];
                float p = 0.0f;
                #pragma unroll
                for (int q = 0; q < 8; ++q)
                    p += buf[q].x * buf[q].x + buf[q].y * buf[q].y + buf[q].z * buf[q].z + buf[q].w * buf[q].w;
                p += __shfl_xor(p, 1);
                p += __shfl_xor(p, 2);
                #pragma unroll
                for (int q = 0; q < 4; ++q) {
                    int c16 = sub * 4 + q;
                    *reinterpret_cast<short8*>(&tCLS[row * DIM + ((c16 ^ (row & 7)) * 8)]) =
                        pack8(buf[2 * q], buf[2 * q + 1]);
                }
                if (sub == 0) sqg[row] = p;
            }
        }
    }

    // ---- strip loop: 8 column tiles of 64; accumulate rn partials in regs ----
    float racc[2][4] = {};
    for (int jt = 0; jt < NJT; ++jt) {
        const int colb = s * CPS + jt * 64;
        __syncthreads();                    // prev tile readers done (jt=0: tCLS visible)
        {
            const int row = t >> 2, sub = t & 3;
            const float4* src = reinterpret_cast<const float4*>(X + (size_t)(colb + row) * DIM + sub * 32);
            float4 buf[8];
            #pragma unroll
            for (int q = 0; q < 8; ++q) buf[q] = src[q];
            float p = 0.0f;
            #pragma unroll
            for (int q = 0; q < 8; ++q)
                p += buf[q].x * buf[q].x + buf[q].y * buf[q].y + buf[q].z * buf[q].z + buf[q].w * buf[q].w;
            p += __shfl_xor(p, 1);
            p += __shfl_xor(p, 2);
            #pragma unroll
            for (int q = 0; q < 4; ++q) {
                int c16 = sub * 4 + q;
                *reinterpret_cast<short8*>(&tCOL[row * DIM + ((c16 ^ (row & 7)) * 8)]) =
                    pack8(buf[2 * q], buf[2 * q + 1]);
            }
            if (sub == 0) sqc[row] = p;
        }
        if (t < 64) tjc[t] = tgt[colb + t];
        __syncthreads();                    // tCOL/sqc/tjc ready

        #pragma unroll
        for (int fi = 0; fi < 2; ++fi) {
            const int rowbase = fi * 64 + w * 16;
            if (rowbase < mm) {             // wave-uniform guard
                const int arow = rowbase + lr;
                f32x4 C[4] = {};
                #pragma unroll
                for (int ks = 0; ks < 4; ++ks) {
                    int cb = ks * 4 + lg;
                    short8 a = *reinterpret_cast<const short8*>(&tCLS[arow * DIM + ((cb ^ (arow & 7)) * 8)]);
                    #pragma unroll
                    for (int fj = 0; fj < 4; ++fj) {
                        int brow = fj * 16 + lr;
                        short8 bb = *reinterpret_cast<const short8*>(&tCOL[brow * DIM + ((cb ^ (brow & 7)) * 8)]);
                        C[fj] = __builtin_amdgcn_mfma_f32_16x16x32_bf16(a, bb, C[fj], 0, 0, 0);
                    }
                }
                // C[fj][r]: p-row = rowbase + lg*4 + r, col = colb + fj*16 + lr
                #pragma unroll
                for (int fj = 0; fj < 4; ++fj) {
                    int jl = fj * 16 + lr;
                    float sc2 = sqc[jl];
                    int   tj  = tjc[jl];
                    #pragma unroll
                    for (int r = 0; r < 4; ++r) {
                        int p = rowbase + lg * 4 + r;
                        float d2 = fmaxf(sqg[p] + sc2 - 2.0f * C[fj][r], 0.0f);
                        float dist = __builtin_amdgcn_sqrtf(d2);
                        float e = __expf(1.0f - dist);
                        bool valid = (tj != c) && (d2 > 0.0f);
                        racc[fi][r] += valid ? e : 0.0f;
                    }
                }
            }
        }
    }

    // ---- write strip partials: reduce across the 16 lr lanes ----
    #pragma unroll
    for (int fi = 0; fi < 2; ++fi)
        #pragma unroll
        for (int r = 0; r < 4; ++r) {
            racc[fi][r] += __shfl_xor(racc[fi][r], 1);
            racc[fi][r] += __shfl_xor(racc[fi][r], 2);
            racc[fi][r] += __shfl_xor(racc[fi][r], 4);
            racc[fi][r] += __shfl_xor(racc[fi][r], 8);
        }
    if (lr == 0) {
        #pragma unroll
        for (int fi = 0; fi < 2; ++fi)
            #pragma unroll
            for (int r = 0; r < 4; ++r) {
                int prow = fi * 64 + w * 16 + lg * 4 + r;
                if (prow < mm)
                    rnP[((size_t)c * MAXM + prow) * NSTRIP + s] = racc[fi][r];
            }
    }

    // ---- class ticket: winner (exactly one, any initial tick value) finishes ----
    __threadfence();                         // release this thread's rnP stores
    __syncthreads();
    if (t == 0) {
        unsigned old = atomicAdd(&tickC[c], 1u);
        s_win = ((old & (NSTRIP - 1)) == (NSTRIP - 1)) ? 1 : 0;
    }
    __syncthreads();
    if (!s_win) return;

    // ================= finisher: positive-pair loss for class c =================
    __threadfence();                         // acquire other strips' rnP stores
    if (t < MAXM) {
        float s2 = 0.0f;
        if (t < mm) {
            float* pp = &rnP[((size_t)c * MAXM + t) * NSTRIP];
            #pragma unroll
            for (int s2i = 0; s2i < NSTRIP; ++s2i) s2 += agentLoad(pp + s2i);
        }
        rng[t] = s2;
    }
    __syncthreads();

    float csum = 0.0f, cpairs = 0.0f;
    const int nfj = (mm + 15) >> 4;
    #pragma unroll
    for (int fi2 = 0; fi2 < 2; ++fi2) {
        const int rowbase = fi2 * 64 + w * 16;
        if (rowbase < mm) {
            const int arow = rowbase + lr;
            f32x4 C2[8] = {};
            #pragma unroll
            for (int ks = 0; ks < 4; ++ks) {
                int cb = ks * 4 + lg;
                short8 a = *reinterpret_cast<const short8*>(&tCLS[arow * DIM + ((cb ^ (arow & 7)) * 8)]);
                #pragma unroll
                for (int fj = 0; fj < 8; ++fj) {
                    if (fj < nfj) {
                        int brow = fj * 16 + lr;
                        short8 bb = *reinterpret_cast<const short8*>(&tCLS[brow * DIM + ((cb ^ (brow & 7)) * 8)]);
                        C2[fj] = __builtin_amdgcn_mfma_f32_16x16x32_bf16(a, bb, C2[fj], 0, 0, 0);
                    }
                }
            }
            #pragma unroll
            for (int fj = 0; fj < 8; ++fj) {
                if (fj < nfj) {
                    int q = fj * 16 + lr;
                    #pragma unroll
                    for (int r = 0; r < 4; ++r) {
                        int p = rowbase + lg * 4 + r;
                        if (q < mm && p < q) {
                            float d2 = fmaxf(sqg[p] + sqg[q] - 2.0f * C2[fj][r], 0.0f);
                            float dist = __builtin_amdgcn_sqrtf(d2);
                            float J = __logf(rng[p] + rng[q]) + dist;
                            if (J > 0.0f) csum += J * J;
                            cpairs += 1.0f;
                        }
                    }
                }
            }
        }
    }

    #pragma unroll
    for (int mr = 1; mr < 64; mr <<= 1) {
        csum   += __shfl_xor(csum, mr);
        cpairs += __shfl_xor(cpairs, mr);
    }
    if (l == 0) { s_red[w] = csum; s_red[8 + w] = cpairs; }
    __syncthreads();
    if (t == 0) {
        res[c * 2]     = s_red[0] + s_red[1] + s_red[2] + s_red[3];
        res[c * 2 + 1] = s_red[8] + s_red[9] + s_red[10] + s_red[11];
        __threadfence();                     // release res before global ticket
        unsigned old2 = atomicAdd(tickG, 1u);
        if ((old2 & (NCLS - 1)) == (NCLS - 1)) {
            __threadfence();                 // acquire all res slots
            float S = 0.0f, N2 = 0.0f;
            for (int cc = 0; cc < NCLS; ++cc) {
                S  += agentLoad(&res[cc * 2]);
                N2 += agentLoad(&res[cc * 2 + 1]);
            }
            out[0] = S / (2.0f * N2);        // len_p = 2 * upper-tri count
        }
    }
}

extern "C" void kernel_launch(void* const* d_in, const int* in_sizes, int n_in,
                              void* d_out, int out_size, void* d_ws, size_t ws_size,
                              hipStream_t stream)
{
    const float* X  = (const float*)d_in[0];
    const int* tgt  = (const int*)d_in[1];
    float* out      = (float*)d_out;

    float*    rnP   = (float*)d_ws;                          // 64*128*8 floats = 256 KB (write-only slots)
    float*    res   = rnP + (size_t)NCLS * MAXM * NSTRIP;    // 128 floats (write-only slots)
    unsigned* tickC = (unsigned*)(res + 2 * NCLS);           // 64 u32 (mod-trick, no init)
    unsigned* tickG = tickC + NCLS;                          // 1 u32  (mod-trick, no init)

    fused_kernel<<<NCLS * NSTRIP, 256, 0, stream>>>(X, tgt, rnP, res, tickC, tickG, out);
}

// Round 10
// 45.094 us; speedup vs baseline: 3.4321x; 3.4321x over previous
//
#include <hip/hip_runtime.h>
#include <hip/hip_bf16.h>
#include <math.h>

typedef short short8 __attribute__((ext_vector_type(8)));
typedef float f32x4 __attribute__((ext_vector_type(4)));

#define NROW 4096
#define DIM  128
#define NCLS 64
#define MAXM 128
#define LCAP 256
#define NBT  64      // 64 row-blocks of 64 rows
#define NTILE 2080   // NBT*(NBT+1)/2 upper-tri 64x64 tiles
#define PS   66      // per-row partial-slot stride (65 slots used)

typedef __attribute__((address_space(3))) unsigned lds_u32;
typedef const __attribute__((address_space(1))) unsigned glb_u32;

__device__ __forceinline__ void gload16(const void* g, void* lds) {
    // 16B/lane; LDS dest = wave-uniform base + lane*16, global src per-lane
    __builtin_amdgcn_global_load_lds((glb_u32*)g, (lds_u32*)lds, 16, 0, 0);
}

__device__ __forceinline__ unsigned short f2bf(float f) {
    unsigned u = __builtin_bit_cast(unsigned, f);
    unsigned r = (u + 0x7fffu + ((u >> 16) & 1u)) >> 16;   // RNE
    return (unsigned short)r;
}

// ---- prep: fp32 row norms, bf16 copy, zero acc/tick (only state needing init) ----
__global__ __launch_bounds__(256) void prep_kernel(const float* __restrict__ X,
        unsigned short* __restrict__ Xb, float* __restrict__ sq,
        float* __restrict__ acc, unsigned* __restrict__ tick)
{
    int t = threadIdx.x;
    int row = blockIdx.x * 8 + (t >> 5);
    int c = t & 31;
    float4 v = *reinterpret_cast<const float4*>(X + (size_t)row * DIM + c * 4);
    float p = v.x * v.x + v.y * v.y + v.z * v.z + v.w * v.w;
    p += __shfl_xor(p, 16, 32);
    p += __shfl_xor(p, 8, 32);
    p += __shfl_xor(p, 4, 32);
    p += __shfl_xor(p, 2, 32);
    p += __shfl_xor(p, 1, 32);
    ushort4 h;
    h.x = f2bf(v.x); h.y = f2bf(v.y); h.z = f2bf(v.z); h.w = f2bf(v.w);
    *reinterpret_cast<ushort4*>(Xb + (size_t)row * DIM + c * 4) = h;
    if (c == 0) sq[row] = p;
    if (blockIdx.x == 0) {
        if (t == 64) { acc[0] = 0.0f; acc[1] = 0.0f; }
        if (t == 65) tick[0] = 0u;
    }
}

// ---- row_neg partials: 64x64 upper-tri tiles, gload_lds staging, write-only P ----
// P[row*PS + s]: s in [0, R(row)]   = j-side partial from tile (s, R)
//                s in (R(row), 64]  = i-side partial from tile (R, s-1)
__global__ __launch_bounds__(256, 4) void rowneg_kernel(
        const unsigned short* __restrict__ Xb, const float* __restrict__ sq,
        const int* __restrict__ tgt, float* __restrict__ P)
{
    const int t = threadIdx.x;
    const int w = t >> 6, l = t & 63, lr = l & 15, lg = l >> 4;

    // invert triangular index: k -> (bi, bj), bi <= bj; off(bi) = bi*NBT - bi(bi-1)/2
    const int k = blockIdx.x;
    int bi = (int)(64.5f - sqrtf(64.5f * 64.5f - 2.0f * (float)k));
    if (bi < 0) bi = 0; if (bi > NBT - 1) bi = NBT - 1;
    while (bi < NBT - 1 && ((bi + 1) * NBT - (((bi + 1) * bi) >> 1)) <= k) ++bi;
    while (bi > 0 && (bi * NBT - ((bi * (bi - 1)) >> 1)) > k) --bi;
    const int bj = bi + (k - (bi * NBT - ((bi * (bi - 1)) >> 1)));
    const int gib = bi * 64, gjb = bj * 64;
    const bool diag = (bi == bj);

    __shared__ __align__(16) unsigned short tA[64 * 128];
    __shared__ __align__(16) unsigned short tB[64 * 128];
    __shared__ float s_sqi[64], s_sqj[64];
    __shared__ float s_cacc[4][64];
    __shared__ int   s_ti[64], s_tj[64];

    // stage: 16 issues each of 1KB; linear LDS dest, inverse-swizzled global source
    #pragma unroll
    for (int kk = 0; kk < 4; ++kk) {
        int q = w * 4 + kk;                     // 1KB chunk
        int row = q * 4 + (l >> 4);             // 4 rows per KB
        int sc = (l & 15) ^ (row & 7);          // inverse-swizzled source chunk
        gload16(Xb + (size_t)(gib + row) * DIM + sc * 8, &tA[q * 512]);
        if (!diag)
            gload16(Xb + (size_t)(gjb + row) * DIM + sc * 8, &tB[q * 512]);
    }
    if (t < 64)       { s_sqi[t] = sq[gib + t]; s_ti[t] = tgt[gib + t]; }
    else if (t < 128) { int u = t - 64; s_sqj[u] = sq[gjb + u]; s_tj[u] = tgt[gjb + u]; }
    __syncthreads();

    const unsigned short* tBp = diag ? tA : tB;
    const int arow = w * 16 + lr;

    f32x4 C[4] = {};
    #pragma unroll
    for (int ks = 0; ks < 4; ++ks) {
        int c = ks * 4 + lg;
        short8 a = *reinterpret_cast<const short8*>(&tA[arow * 128 + ((c ^ (arow & 7)) * 8)]);
        #pragma unroll
        for (int fj = 0; fj < 4; ++fj) {
            int brow = fj * 16 + lr;
            short8 bb = *reinterpret_cast<const short8*>(&tBp[brow * 128 + ((c ^ (brow & 7)) * 8)]);
            C[fj] = __builtin_amdgcn_mfma_f32_16x16x32_bf16(a, bb, C[fj], 0, 0, 0);
        }
    }

    // C[fj][r]: i = gib + w*16 + lg*4 + r, j = gjb + fj*16 + lr
    const int ibase = w * 16 + lg * 4;
    float sqi[4]; int ti[4];
    #pragma unroll
    for (int r = 0; r < 4; ++r) { sqi[r] = s_sqi[ibase + r]; ti[r] = s_ti[ibase + r]; }

    float racc[4] = {0.f, 0.f, 0.f, 0.f};
    float cacc[4] = {0.f, 0.f, 0.f, 0.f};
    #pragma unroll
    for (int fj = 0; fj < 4; ++fj) {
        int jl = fj * 16 + lr;
        float sqj = s_sqj[jl];
        int   tj  = s_tj[jl];
        int   gj  = gjb + jl;
        #pragma unroll
        for (int r = 0; r < 4; ++r) {
            int gi = gib + ibase + r;
            float d2 = fmaxf(sqi[r] + sqj - 2.0f * C[fj][r], 0.0f);
            float dist = __builtin_amdgcn_sqrtf(d2);
            float e = __expf(1.0f - dist);
            bool valid = (gi < gj) && (ti[r] != tj) && (d2 > 0.0f);
            e = valid ? e : 0.0f;
            racc[r] += e;
            cacc[fj] += e;
        }
    }

    // i-side row partials: reduce across lr (16 lanes), store slot bj+1 (no atomics)
    #pragma unroll
    for (int r = 0; r < 4; ++r) {
        racc[r] += __shfl_xor(racc[r], 1);
        racc[r] += __shfl_xor(racc[r], 2);
        racc[r] += __shfl_xor(racc[r], 4);
        racc[r] += __shfl_xor(racc[r], 8);
    }
    if (lr == 0) {
        #pragma unroll
        for (int r = 0; r < 4; ++r)
            P[(size_t)(gib + ibase + r) * PS + (bj + 1)] = racc[r];
    }
    // j-side col partials: reduce across lg within wave, combine 4 waves, store slot bi
    #pragma unroll
    for (int fj = 0; fj < 4; ++fj) {
        cacc[fj] += __shfl_xor(cacc[fj], 16);
        cacc[fj] += __shfl_xor(cacc[fj], 32);
    }
    if (lg == 0) {
        #pragma unroll
        for (int fj = 0; fj < 4; ++fj) s_cacc[w][fj * 16 + lr] = cacc[fj];
    }
    __syncthreads();
    if (t < 64) {
        float cs = s_cacc[0][t] + s_cacc[1][t] + s_cacc[2][t] + s_cacc[3][t];
        P[(size_t)(gjb + t) * PS + bi] = cs;
    }
}

// ---- per-class positive loss; 2 blocks/class (h = p-row half); last block finalizes ----
__global__ __launch_bounds__(256) void loss_kernel(
        const unsigned short* __restrict__ Xb, const float* __restrict__ X,
        const float* __restrict__ sq, const int* __restrict__ tgt,
        const float* __restrict__ P,
        float* __restrict__ acc, unsigned* __restrict__ tick, float* __restrict__ out)
{
    const int c = blockIdx.x >> 1;
    const int h = blockIdx.x & 1;

    __shared__ __align__(16) unsigned short tX[MAXM * DIM];
    __shared__ float sqg[MAXM], rng[MAXM];
    __shared__ int   s_idx[LCAP];
    __shared__ int   s_wsum[4];
    __shared__ float s_red[16];

    const int t = threadIdx.x;
    const int w = t >> 6, l = t & 63, lr = l & 15, lg = l >> 4;

    float csum = 0.0f, cpairs = 0.0f;
    int mtot, mm, nfj;

    // ---- build ordered class row list by scanning tgt (no global scatter state) ----
    {
        const int rbase = t * 16;
        int tv[16];
        {
            int4 a = *reinterpret_cast<const int4*>(tgt + rbase);
            int4 b = *reinterpret_cast<const int4*>(tgt + rbase + 4);
            int4 d = *reinterpret_cast<const int4*>(tgt + rbase + 8);
            int4 e = *reinterpret_cast<const int4*>(tgt + rbase + 12);
            tv[0]=a.x; tv[1]=a.y; tv[2]=a.z; tv[3]=a.w;
            tv[4]=b.x; tv[5]=b.y; tv[6]=b.z; tv[7]=b.w;
            tv[8]=d.x; tv[9]=d.y; tv[10]=d.z; tv[11]=d.w;
            tv[12]=e.x; tv[13]=e.y; tv[14]=e.z; tv[15]=e.w;
        }
        int cnt = 0;
        #pragma unroll
        for (int k2 = 0; k2 < 16; ++k2) cnt += (tv[k2] == c) ? 1 : 0;
        int sc = cnt;                                   // wave inclusive scan
        #pragma unroll
        for (int d2 = 1; d2 < 64; d2 <<= 1) {
            int u = __shfl_up(sc, d2);
            if (l >= d2) sc += u;
        }
        if (l == 63) s_wsum[w] = sc;
        __syncthreads();
        int woff = 0;
        if (w > 0) woff += s_wsum[0];
        if (w > 1) woff += s_wsum[1];
        if (w > 2) woff += s_wsum[2];
        int off = woff + sc - cnt;                      // exclusive prefix
        #pragma unroll
        for (int k2 = 0; k2 < 16; ++k2) {
            if (tv[k2] == c) { if (off < LCAP) s_idx[off] = rbase + k2; ++off; }
        }
        mtot = s_wsum[0] + s_wsum[1] + s_wsum[2] + s_wsum[3];
        // CRASH FIX (R9): pad unwritten list entries with a valid row index so the
        // rounded-up staging loop never reads uninitialized LDS as a gather index.
        if (t >= mtot && t < MAXM) s_idx[t] = 0;
    }
    mm  = mtot < MAXM ? mtot : MAXM;
    nfj = (mm + 15) >> 4;
    __syncthreads();                                    // s_idx ready (incl. padding)

    // h=1 has no p-rows when mm<=64 (fallback is h=0's job): bare tick and leave
    if (h == 1 && mm <= 64) goto tickout;

    // ---- rn for gathered rows: sum the 65 tile partials; sq/norms from prep ----
    if (t < MAXM) {
        float s2 = 0.0f, q2 = 0.0f;
        if (t < mm) {
            const float* pp = P + (size_t)s_idx[t] * PS;
            #pragma unroll 5
            for (int s = 0; s < 65; ++s) s2 += pp[s];
            q2 = sq[s_idx[t]];
        }
        rng[t] = s2;
        sqg[t] = q2;
    }
    // ---- gathered stage: per-lane gather + swizzle source, linear LDS dest ----
    #pragma unroll
    for (int kk = 0; kk < 8; ++kk) {
        int q = w * 8 + kk;
        int row = q * 4 + (l >> 4);
        if (row < ((mm + 3) & ~3)) {
            int sc = (l & 15) ^ (row & 7);
            gload16(Xb + (size_t)s_idx[row] * DIM + sc * 8, &tX[q * 512]);
        }
    }
    __syncthreads();

    {
        const int rowbase = h * 64 + w * 16;
        if (rowbase < mm) {                              // wave-uniform guard
            f32x4 C[8] = {};
            const int arow = rowbase + lr;
            #pragma unroll
            for (int ks = 0; ks < 4; ++ks) {
                int cb = ks * 4 + lg;
                short8 a = *reinterpret_cast<const short8*>(&tX[arow * DIM + ((cb ^ (arow & 7)) * 8)]);
                #pragma unroll
                for (int fj = 0; fj < 8; ++fj) {
                    if (fj < nfj) {
                        int brow = fj * 16 + lr;
                        short8 bb = *reinterpret_cast<const short8*>(&tX[brow * DIM + ((cb ^ (brow & 7)) * 8)]);
                        C[fj] = __builtin_amdgcn_mfma_f32_16x16x32_bf16(a, bb, C[fj], 0, 0, 0);
                    }
                }
            }
            #pragma unroll
            for (int fj = 0; fj < 8; ++fj) {
                if (fj < nfj) {
                    int q = fj * 16 + lr;
                    #pragma unroll
                    for (int r = 0; r < 4; ++r) {
                        int p = rowbase + lg * 4 + r;
                        if (q < mm && p < q) {
                            float d2 = fmaxf(sqg[p] + sqg[q] - 2.0f * C[fj][r], 0.0f);
                            float dist = __builtin_amdgcn_sqrtf(d2);
                            float J = __logf(rng[p] + rng[q]) + dist;
                            if (J > 0.0f) csum += J * J;
                            cpairs += 1.0f;
                        }
                    }
                }
            }
        }

        // fallback for improbably large classes (fp32, h=0 only, practically unreachable)
        if (h == 0 && mtot > MAXM) {
            int mq = mtot < LCAP ? mtot : LCAP;
            for (int q = MAXM; q < mq; ++q) {
                int rq = s_idx[q];
                const float4* xb = reinterpret_cast<const float4*>(X + (size_t)rq * DIM);
                float sqq = sq[rq];
                float rnq = 0.0f;
                for (int s = 0; s < 65; ++s) rnq += P[(size_t)rq * PS + s];
                for (int p2 = t; p2 < q; p2 += 256) {
                    int rp = s_idx[p2];
                    const float4* xa = reinterpret_cast<const float4*>(X + (size_t)rp * DIM);
                    float d = 0.0f;
                    for (int kq = 0; kq < 32; ++kq) {
                        float4 av = xa[kq], bv = xb[kq];
                        d += av.x * bv.x + av.y * bv.y + av.z * bv.z + av.w * bv.w;
                    }
                    float rnp = 0.0f;
                    for (int s = 0; s < 65; ++s) rnp += P[(size_t)rp * PS + s];
                    float d2 = fmaxf(sq[rp] + sqq - 2.0f * d, 0.0f);
                    float dist = __builtin_amdgcn_sqrtf(d2);
                    float J = __logf(rnp + rnq) + dist;
                    if (J > 0.0f) csum += J * J;
                    cpairs += 1.0f;
                }
            }
        }

        #pragma unroll
        for (int mr = 1; mr < 64; mr <<= 1) {
            csum   += __shfl_xor(csum, mr);
            cpairs += __shfl_xor(cpairs, mr);
        }
        if (l == 0) { s_red[w] = csum; s_red[8 + w] = cpairs; }
        __syncthreads();
        if (t == 0) {
            float bs = s_red[0] + s_red[1] + s_red[2] + s_red[3];
            float bc = s_red[8] + s_red[9] + s_red[10] + s_red[11];
            if (bs != 0.0f || bc != 0.0f) {
                atomicAdd(&acc[0], bs);
                atomicAdd(&acc[1], bc);
            }
        }
    }

tickout:
    __threadfence();
    if (t == 0) {
        unsigned old = atomicAdd(tick, 1u);
        if (old == 2 * NCLS - 1) {
            float s  = atomicAdd(&acc[0], 0.0f);   // coherent device-scope reads
            float n2 = atomicAdd(&acc[1], 0.0f);
            out[0] = s / (2.0f * n2);              // len_p = 2 * upper-tri count
        }
    }
}

extern "C" void kernel_launch(void* const* d_in, const int* in_sizes, int n_in,
                              void* d_out, int out_size, void* d_ws, size_t ws_size,
                              hipStream_t stream)
{
    const float* X  = (const float*)d_in[0];
    const int* tgt  = (const int*)d_in[1];
    float* out      = (float*)d_out;

    char* ws = (char*)d_ws;
    unsigned short* Xb = (unsigned short*)ws;                 // 1 MB bf16 copy
    float*    sq   = (float*)(ws + (size_t)NROW * DIM * 2);   // 16 KB
    float*    P    = sq + NROW;                               // 4096*66*4 ≈ 1.06 MB (write-only)
    float*    acc  = P + (size_t)NROW * PS;                   // 2 floats (zeroed by prep)
    unsigned* tick = (unsigned*)(acc + 2);                    // 1 uint   (zeroed by prep)

    prep_kernel<<<NROW / 8, 256, 0, stream>>>(X, Xb, sq, acc, tick);
    rowneg_kernel<<<NTILE, 256, 0, stream>>>(Xb, sq, tgt, P);
    loss_kernel<<<2 * NCLS, 256, 0, stream>>>(Xb, X, sq, tgt, P, acc, tick, out);
}